// Round 14
// baseline (183.462 us; speedup 1.0000x reference)
//
#include <hip/hip_runtime.h>
#include <hip/hip_bf16.h>

typedef float float4a __attribute__((ext_vector_type(4), aligned(4)));
typedef float float2a __attribute__((ext_vector_type(2), aligned(4)));
typedef short bfrag   __attribute__((ext_vector_type(8)));   // 8 bf16 (MFMA A/B frag)
typedef float f32x4   __attribute__((ext_vector_type(4)));

// ---------------- dims ----------------
#define P1W_PAD 128            // p1 row stride (f32), cols 123..127 zero
#define APAD 56064             // A row stride (f32) = 219*256, elems 55815.. zero
#define KFC 55815
#define CHUNK 256
#define NCHUNK 219
#define NFC1 120

// ws byte offsets
#define oP1B   ((size_t)0)            // 24,182,784
#define oAB    ((size_t)24182784)     // 14,352,384
#define oPARTB ((size_t)38535168)     // 219*7680*4 = 6,727,680
#define oP2B   ((size_t)45262848)     // 8*7680*4   =   245,760

// ============ conv1 (3->6,k5,s2,p1)+ReLU+pool2s1 -> p1 f32[64][6][123][128] [r8-proven] ============
__global__ __launch_bounds__(256) void conv1_pool(const float* __restrict__ x,
        const float* __restrict__ w, const float* __restrict__ bias,
        float* __restrict__ p1) {
    __shared__ float ex[8 * 6 * 128];     // 24.6 KB
    const int tid = threadIdx.x;
    const int G = blockIdx.x;
    const int b = blockIdx.y;
    const int t = tid >> 5;
    const int s = tid & 31;
    const int r = 7 * G + t;
    const bool act = (r < 124) && (s < 31);

    if (act) {
        float acc[6][4];
        #pragma unroll
        for (int c = 0; c < 6; ++c) {
            const float bz = bias[c];
            #pragma unroll
            for (int j = 0; j < 4; ++j) acc[c][j] = bz;
        }
        for (int ic = 0; ic < 3; ++ic) {
            const float* xpl = x + (size_t)(b * 3 + ic) * 62500;
            #pragma unroll
            for (int ky = 0; ky < 5; ++ky) {
                const int iy = 2 * r - 1 + ky;
                if (iy < 0) continue;                       // top pad (bottom never hit)
                const float* rp = xpl + iy * 250 + 8 * s;
                float a[11];
                a[0] = (s > 0) ? rp[-1] : 0.f;              // left pad
                *(float4a*)&a[1] = *(const float4a*)rp;
                *(float4a*)&a[5] = *(const float4a*)(rp + 4);
                *(float2a*)&a[9] = *(const float2a*)(rp + 8);
                const float* wb = w + ic * 25 + ky * 5;     // + c*75 + kx (uniform s_loads)
                #pragma unroll
                for (int c = 0; c < 6; ++c) {
                    #pragma unroll
                    for (int kx = 0; kx < 5; ++kx) {
                        const float wv = wb[c * 75 + kx];
                        #pragma unroll
                        for (int j = 0; j < 4; ++j)
                            acc[c][j] = fmaf(a[2 * j + kx], wv, acc[c][j]);
                    }
                }
            }
        }
        #pragma unroll
        for (int c = 0; c < 6; ++c)
            *(float4*)&ex[(t * 6 + c) * 128 + 4 * s] = *(float4*)&acc[c][0];
    }
    __syncthreads();
    const int np = min(7, 123 - 7 * G);                     // pool rows this block
    for (int idx = tid; idx < np * 768; idx += 256) {       // 768 = 6*128
        const int p   = idx / 768;
        const int rem = idx - p * 768;                      // (768 != 2^n: no & trick)
        const int c   = rem >> 7;
        const int pc  = rem & 127;
        float v = 0.f;
        if (pc < 123) {
            const float* r0 = &ex[((p    ) * 6 + c) * 128 + pc];
            const float* r1 = &ex[((p + 1) * 6 + c) * 128 + pc];
            v = fmaxf(fmaxf(fmaxf(r0[0], r0[1]), fmaxf(r1[0], r1[1])), 0.f);
        }
        p1[((size_t)(b * 6 + c) * 123 + (7 * G + p)) * P1W_PAD + pc] = v;
    }
}

// ============ conv2 (6->15,k3,s2,p1)+ReLU+pool2s1 -> A f32[64][56064] [r8-proven] ============
__global__ __launch_bounds__(256) void conv2_pool(const float* __restrict__ p1,
        const float* __restrict__ w, const float* __restrict__ bias,
        float* __restrict__ A) {
    __shared__ float ex[16 * 15 * 64];    // 61.4 KB
    const int tid = threadIdx.x;
    const int G = blockIdx.x;
    const int b = blockIdx.y;
    const int t = tid >> 4;
    const int s = tid & 15;
    const int r = 15 * G + t;
    const bool act = (r < 62);

    if (act) {
        float acc[15][4];
        #pragma unroll
        for (int c = 0; c < 15; ++c) {
            const float bz = bias[c];
            #pragma unroll
            for (int j = 0; j < 4; ++j) acc[c][j] = bz;
        }
        for (int ic = 0; ic < 6; ++ic) {
            const float* pl = p1 + (size_t)(b * 6 + ic) * 123 * P1W_PAD;
            #pragma unroll
            for (int ky = 0; ky < 3; ++ky) {
                const int iy = 2 * r - 1 + ky;
                if (iy < 0 || iy > 122) continue;
                const float* rp = pl + iy * P1W_PAD + 8 * s;
                float a[9];
                a[0] = (s > 0) ? rp[-1] : 0.f;              // left pad (cols>=123 are 0)
                *(float4a*)&a[1] = *(const float4a*)rp;
                *(float4a*)&a[5] = *(const float4a*)(rp + 4);
                const float* wb = w + ic * 9 + ky * 3;      // + c*54 + kx (uniform)
                #pragma unroll
                for (int c = 0; c < 15; ++c) {
                    #pragma unroll
                    for (int kx = 0; kx < 3; ++kx) {
                        const float wv = wb[c * 54 + kx];
                        #pragma unroll
                        for (int j = 0; j < 4; ++j)
                            acc[c][j] = fmaf(a[2 * j + kx], wv, acc[c][j]);
                    }
                }
            }
        }
        #pragma unroll
        for (int c = 0; c < 15; ++c)
            *(float4*)&ex[(t * 15 + c) * 64 + 4 * s] = *(float4*)&acc[c][0];
    }
    __syncthreads();
    const int np = min(15, 61 - 15 * G);
    for (int idx = tid; idx < np * 915; idx += 256) {       // 915 = 15*61 (true modulo)
        const int p   = idx / 915;
        const int rem = idx % 915;
        const int c   = rem / 61;
        const int pc  = rem % 61;
        const float* r0 = &ex[((p    ) * 15 + c) * 64 + pc];
        const float* r1 = &ex[((p + 1) * 15 + c) * 64 + pc];
        const float v = fmaxf(fmaxf(r0[0], r0[1]), fmaxf(r1[0], r1[1]));
        A[(size_t)b * APAD + c * 3721 + (15 * G + p) * 61 + pc] = fmaxf(v, 0.f);
    }
    if (G == 0)                                             // zero the K-pad tail
        for (int i2 = tid; i2 < 249; i2 += 256)
            A[(size_t)b * APAD + KFC + i2] = 0.f;
}

// ============ fc1 split-K MFMA [r10-verbatim; measured r13: ~18.5 us] ============
// part[c][64 b][120 o]; grid (219,2); block 256 = 4 mtile waves; nth = N-half
__global__ __launch_bounds__(256) void fc1_s1(const float* __restrict__ A,
        const float* __restrict__ W, float* __restrict__ part) {
    const int cBlk = blockIdx.x;
    const int nth  = blockIdx.y;          // 0/1
    const int k0 = cBlk * CHUNK;
    const int tid = threadIdx.x;
    const int lane  = tid & 63;
    const int mtile = tid >> 6;           // 0..3
    const int ocol  = lane & 15;
    const int kq    = lane >> 4;          // 0..3 (k-quad within 32-wide MFMA K)
    const int arow  = mtile * 16 + ocol;

    const float* ab = A + (size_t)arow * APAD + k0 + kq * 8;
    const float* wb[4];
    #pragma unroll
    for (int ntl = 0; ntl < 4; ++ntl) {
        const int o = (nth * 4 + ntl) * 16 + ocol;
        wb[ntl] = W + (size_t)min(o, NFC1 - 1) * KFC + k0 + kq * 8;
    }

    f32x4 acc[4];
    #pragma unroll
    for (int n = 0; n < 4; ++n) acc[n] = (f32x4){0.f, 0.f, 0.f, 0.f};

    const bool full = (cBlk != NCHUNK - 1);
    #pragma unroll 2
    for (int ks = 0; ks < 8; ++ks) {
        float af[8];
        *(float4a*)&af[0] = *(const float4a*)(ab + ks * 32);
        *(float4a*)&af[4] = *(const float4a*)(ab + ks * 32 + 4);
        bfrag ah, al;
        #pragma unroll
        for (int e = 0; e < 8; ++e) {
            const unsigned u = __float_as_uint(af[e]);
            ah[e] = (short)(u >> 16);                            // hi = trunc-bf16
            const float rres = af[e] - __uint_as_float(u & 0xffff0000u);
            al[e] = (short)(__float_as_uint(rres) >> 16);        // lo = trunc-bf16(res)
        }
        #pragma unroll
        for (int ntl = 0; ntl < 4; ++ntl) {
            float wf[8];
            if (full) {
                *(float4a*)&wf[0] = *(const float4a*)(wb[ntl] + ks * 32);
                *(float4a*)&wf[4] = *(const float4a*)(wb[ntl] + ks * 32 + 4);
            } else {                                        // last chunk: guard OOB (W alloc end)
                const int kg = k0 + ks * 32 + kq * 8;
                #pragma unroll
                for (int e = 0; e < 8; ++e)
                    wf[e] = (kg + e < KFC) ? wb[ntl][ks * 32 + e] : 0.f;
            }
            bfrag wh, wl;
            #pragma unroll
            for (int e = 0; e < 8; ++e) {
                const unsigned u = __float_as_uint(wf[e]);
                wh[e] = (short)(u >> 16);
                const float rres = wf[e] - __uint_as_float(u & 0xffff0000u);
                wl[e] = (short)(__float_as_uint(rres) >> 16);
            }
            acc[ntl] = __builtin_amdgcn_mfma_f32_16x16x32_bf16(ah, wh, acc[ntl], 0, 0, 0);
            acc[ntl] = __builtin_amdgcn_mfma_f32_16x16x32_bf16(al, wh, acc[ntl], 0, 0, 0);
            acc[ntl] = __builtin_amdgcn_mfma_f32_16x16x32_bf16(ah, wl, acc[ntl], 0, 0, 0);
        }
    }
    #pragma unroll
    for (int ntl = 0; ntl < 4; ++ntl) {
        const int o = (nth * 4 + ntl) * 16 + ocol;
        if (o < NFC1) {
            #pragma unroll
            for (int rr = 0; rr < 4; ++rr) {
                const int brow = mtile * 16 + kq * 4 + rr;  // C/D: row=(l>>4)*4+reg, col=l&15
                part[((size_t)cBlk * 64 + brow) * NFC1 + o] = acc[ntl][rr];
            }
        }
    }
}

// ============ segment reduce: part2[8][7680] (219 = 3x28 + 5x27 chunks) ============
__global__ __launch_bounds__(256) void fc1_s2a(const float* __restrict__ part,
        float* __restrict__ part2) {
    const int idx = blockIdx.x * 256 + threadIdx.x;   // 61440
    const int seg = idx / 7680;
    const int r   = idx % 7680;
    const int c0 = seg * 27 + min(seg, 3);
    const int n  = 27 + (seg < 3 ? 1 : 0);
    float s = 0.f;
    for (int c = c0; c < c0 + n; ++c) s += part[(size_t)c * 7680 + r];
    part2[idx] = s;
}

// ============ tail: fc1 finish + fc2 rows 0..3 + fidelity + classifier + softmax ============
__global__ __launch_bounds__(64) void tail_k(const float* __restrict__ part2,
        const float* __restrict__ fc1b,
        const float* __restrict__ fc2w, const float* __restrict__ fc2b,
        const float* __restrict__ centers,
        const float* __restrict__ w1, const float* __restrict__ b1,
        const float* __restrict__ w2, const float* __restrict__ b2,
        const float* __restrict__ w3, const float* __restrict__ b3,
        float* __restrict__ out) {
    const int b = blockIdx.x;
    const int lane = threadIdx.x;
    __shared__ float h[120];
    __shared__ float feat[4];
    __shared__ float bufA[64];
    __shared__ float bufB[64];

    for (int o = lane; o < NFC1; o += 64) {
        float sv = fc1b[o];
        #pragma unroll
        for (int g = 0; g < 8; ++g) sv += part2[g * 7680 + b * NFC1 + o];
        h[o] = fmaxf(sv, 0.f);
    }
    __syncthreads();

    const int j = lane >> 4, p = lane & 15;
    float sv = 0.f;
    for (int o = p; o < NFC1; o += 16) sv = fmaf(fc2w[j * NFC1 + o], h[o], sv);
    #pragma unroll
    for (int off = 8; off; off >>= 1) sv += __shfl_xor(sv, off, 16);
    if (p == 0) feat[j] = fmaxf(sv + fc2b[j], 0.f);
    __syncthreads();

    float prod = 1.f;
    #pragma unroll
    for (int i = 0; i < 4; ++i) prod *= cosf(0.5f * (feat[i] - centers[lane * 84 + i]));
    bufA[lane] = fabsf(prod);
    __syncthreads();

    float s1 = b1[lane];
    for (int jj = 0; jj < 64; ++jj) s1 = fmaf(w1[lane * 64 + jj], bufA[jj], s1);
    bufB[lane] = fmaxf(s1, 0.f);
    __syncthreads();

    float s2 = b2[lane];
    for (int jj = 0; jj < 64; ++jj) s2 = fmaf(w2[lane * 64 + jj], bufB[jj], s2);
    bufA[lane] = fmaxf(s2, 0.f);
    __syncthreads();

    if (lane < 2) {
        float s3 = b3[lane];
        for (int jj = 0; jj < 64; ++jj) s3 = fmaf(w3[lane * 64 + jj], bufA[jj], s3);
        const float other = __shfl_xor(s3, 1, 2);
        const float m = fmaxf(s3, other);
        const float e = expf(s3 - m), eo = expf(other - m);
        out[b * 2 + lane] = e / (e + eo);
    }
}

// ---------------- launcher ----------------
extern "C" void kernel_launch(void* const* d_in, const int* in_sizes, int n_in,
                              void* d_out, int out_size, void* d_ws, size_t ws_size,
                              hipStream_t stream) {
    const float* x       = (const float*)d_in[0];
    const float* conv1_w = (const float*)d_in[1];
    const float* conv1_b = (const float*)d_in[2];
    const float* conv2_w = (const float*)d_in[3];
    const float* conv2_b = (const float*)d_in[4];
    const float* fc1_w   = (const float*)d_in[5];
    const float* fc1_b   = (const float*)d_in[6];
    const float* fc2_w   = (const float*)d_in[7];
    const float* fc2_b   = (const float*)d_in[8];
    const float* centers = (const float*)d_in[9];
    const float* cls_w1  = (const float*)d_in[10];
    const float* cls_b1  = (const float*)d_in[11];
    const float* cls_w2  = (const float*)d_in[12];
    const float* cls_b2  = (const float*)d_in[13];
    const float* cls_w3  = (const float*)d_in[14];
    const float* cls_b3  = (const float*)d_in[15];
    char* ws = (char*)d_ws;
    float* outp = (float*)d_out;

    float* p1    = (float*)(ws + oP1B);
    float* Abuf  = (float*)(ws + oAB);
    float* partb = (float*)(ws + oPARTB);
    float* part2 = (float*)(ws + oP2B);

    // MEASUREMENT: conv1_pool launched 5x (idempotent). conv1_time = (dur_us - 86.0)/4.
    hipLaunchKernelGGL(conv1_pool, dim3(18, 64), dim3(256), 0, stream, x, conv1_w, conv1_b, p1);
    hipLaunchKernelGGL(conv1_pool, dim3(18, 64), dim3(256), 0, stream, x, conv1_w, conv1_b, p1);
    hipLaunchKernelGGL(conv1_pool, dim3(18, 64), dim3(256), 0, stream, x, conv1_w, conv1_b, p1);
    hipLaunchKernelGGL(conv1_pool, dim3(18, 64), dim3(256), 0, stream, x, conv1_w, conv1_b, p1);
    hipLaunchKernelGGL(conv1_pool, dim3(18, 64), dim3(256), 0, stream, x, conv1_w, conv1_b, p1);
    hipLaunchKernelGGL(conv2_pool, dim3(5, 64), dim3(256), 0, stream, p1, conv2_w, conv2_b, Abuf);
    hipLaunchKernelGGL(fc1_s1, dim3(NCHUNK, 2), dim3(256), 0, stream, Abuf, fc1_w, partb);
    hipLaunchKernelGGL(fc1_s2a, dim3(240), dim3(256), 0, stream, partb, part2);
    hipLaunchKernelGGL(tail_k, dim3(64), dim3(64), 0, stream,
                       part2, fc1_b, fc2_w, fc2_b, centers,
                       cls_w1, cls_b1, cls_w2, cls_b2, cls_w3, cls_b3, outp);
}

// Round 15
// 160.331 us; speedup vs baseline: 1.1443x; 1.1443x over previous
//
#include <hip/hip_runtime.h>
#include <hip/hip_bf16.h>

typedef float float4a __attribute__((ext_vector_type(4), aligned(4)));
typedef float float2a __attribute__((ext_vector_type(2), aligned(4)));
typedef short bfrag   __attribute__((ext_vector_type(8)));   // 8 bf16 (MFMA A/B frag)
typedef float f32x4   __attribute__((ext_vector_type(4)));

// ---------------- dims ----------------
#define P1W_PAD 128            // p1 row stride (f32), cols 123..127 zero
#define APAD 56064             // A row stride (f32) = 219*256, elems 55815.. zero
#define KFC 55815
#define CHUNK 256
#define NCHUNK 219
#define NFC1 120

// ws byte offsets
#define oP1B   ((size_t)0)            // 24,182,784
#define oAB    ((size_t)24182784)     // 14,352,384
#define oPARTB ((size_t)38535168)     // 219*7680*4 = 6,727,680
#define oP2B   ((size_t)45262848)     // 8*7680*4   =   245,760

// ============ conv1 (3->6,k5,s2,p1)+ReLU+pool2s1 -> p1 f32[64][6][123][128] ============
// DIAGNOSTIC: reps runtime arg — body repeated (idempotent), counters visible in top-5
__global__ __launch_bounds__(256) void conv1_pool(const float* __restrict__ x,
        const float* __restrict__ w, const float* __restrict__ bias,
        float* __restrict__ p1, int reps) {
    __shared__ float ex[8 * 6 * 128];     // 24.6 KB
    const int tid = threadIdx.x;
    const int G = blockIdx.x;
    const int b = blockIdx.y;
    const int t = tid >> 5;
    const int s = tid & 31;
    const int r = 7 * G + t;
    const bool act = (r < 124) && (s < 31);

    #pragma unroll 1
    for (int rep = 0; rep < reps; ++rep) {
        if (act) {
            float acc[6][4];
            #pragma unroll
            for (int c = 0; c < 6; ++c) {
                const float bz = bias[c];
                #pragma unroll
                for (int j = 0; j < 4; ++j) acc[c][j] = bz;
            }
            for (int ic = 0; ic < 3; ++ic) {
                const float* xpl = x + (size_t)(b * 3 + ic) * 62500;
                #pragma unroll
                for (int ky = 0; ky < 5; ++ky) {
                    const int iy = 2 * r - 1 + ky;
                    if (iy < 0) continue;                       // top pad (bottom never hit)
                    const float* rp = xpl + iy * 250 + 8 * s;
                    float a[11];
                    a[0] = (s > 0) ? rp[-1] : 0.f;              // left pad
                    *(float4a*)&a[1] = *(const float4a*)rp;
                    *(float4a*)&a[5] = *(const float4a*)(rp + 4);
                    *(float2a*)&a[9] = *(const float2a*)(rp + 8);
                    const float* wb = w + ic * 25 + ky * 5;     // + c*75 + kx (uniform s_loads)
                    #pragma unroll
                    for (int c = 0; c < 6; ++c) {
                        #pragma unroll
                        for (int kx = 0; kx < 5; ++kx) {
                            const float wv = wb[c * 75 + kx];
                            #pragma unroll
                            for (int j = 0; j < 4; ++j)
                                acc[c][j] = fmaf(a[2 * j + kx], wv, acc[c][j]);
                        }
                    }
                }
            }
            #pragma unroll
            for (int c = 0; c < 6; ++c)
                *(float4*)&ex[(t * 6 + c) * 128 + 4 * s] = *(float4*)&acc[c][0];
        }
        __syncthreads();
        const int np = min(7, 123 - 7 * G);                     // pool rows this block
        for (int idx = tid; idx < np * 768; idx += 256) {       // 768 = 6*128
            const int p   = idx / 768;
            const int rem = idx - p * 768;                      // (768 != 2^n: no & trick)
            const int c   = rem >> 7;
            const int pc  = rem & 127;
            float v = 0.f;
            if (pc < 123) {
                const float* r0 = &ex[((p    ) * 6 + c) * 128 + pc];
                const float* r1 = &ex[((p + 1) * 6 + c) * 128 + pc];
                v = fmaxf(fmaxf(fmaxf(r0[0], r0[1]), fmaxf(r1[0], r1[1])), 0.f);
            }
            p1[((size_t)(b * 6 + c) * 123 + (7 * G + p)) * P1W_PAD + pc] = v;
        }
        __syncthreads();                                        // protect ex across reps
    }
}

// ============ conv2 (6->15,k3,s2,p1)+ReLU+pool2s1 -> A f32[64][56064] ============
// DIAGNOSTIC: reps runtime arg
__global__ __launch_bounds__(256) void conv2_pool(const float* __restrict__ p1,
        const float* __restrict__ w, const float* __restrict__ bias,
        float* __restrict__ A, int reps) {
    __shared__ float ex[16 * 15 * 64];    // 61.4 KB
    const int tid = threadIdx.x;
    const int G = blockIdx.x;
    const int b = blockIdx.y;
    const int t = tid >> 4;
    const int s = tid & 15;
    const int r = 15 * G + t;
    const bool act = (r < 62);

    #pragma unroll 1
    for (int rep = 0; rep < reps; ++rep) {
        if (act) {
            float acc[15][4];
            #pragma unroll
            for (int c = 0; c < 15; ++c) {
                const float bz = bias[c];
                #pragma unroll
                for (int j = 0; j < 4; ++j) acc[c][j] = bz;
            }
            for (int ic = 0; ic < 6; ++ic) {
                const float* pl = p1 + (size_t)(b * 6 + ic) * 123 * P1W_PAD;
                #pragma unroll
                for (int ky = 0; ky < 3; ++ky) {
                    const int iy = 2 * r - 1 + ky;
                    if (iy < 0 || iy > 122) continue;
                    const float* rp = pl + iy * P1W_PAD + 8 * s;
                    float a[9];
                    a[0] = (s > 0) ? rp[-1] : 0.f;              // left pad (cols>=123 are 0)
                    *(float4a*)&a[1] = *(const float4a*)rp;
                    *(float4a*)&a[5] = *(const float4a*)(rp + 4);
                    const float* wb = w + ic * 9 + ky * 3;      // + c*54 + kx (uniform)
                    #pragma unroll
                    for (int c = 0; c < 15; ++c) {
                        #pragma unroll
                        for (int kx = 0; kx < 3; ++kx) {
                            const float wv = wb[c * 54 + kx];
                            #pragma unroll
                            for (int j = 0; j < 4; ++j)
                                acc[c][j] = fmaf(a[2 * j + kx], wv, acc[c][j]);
                        }
                    }
                }
            }
            #pragma unroll
            for (int c = 0; c < 15; ++c)
                *(float4*)&ex[(t * 15 + c) * 64 + 4 * s] = *(float4*)&acc[c][0];
        }
        __syncthreads();
        const int np = min(15, 61 - 15 * G);
        for (int idx = tid; idx < np * 915; idx += 256) {       // 915 = 15*61 (true modulo)
            const int p   = idx / 915;
            const int rem = idx % 915;
            const int c   = rem / 61;
            const int pc  = rem % 61;
            const float* r0 = &ex[((p    ) * 15 + c) * 64 + pc];
            const float* r1 = &ex[((p + 1) * 15 + c) * 64 + pc];
            const float v = fmaxf(fmaxf(r0[0], r0[1]), fmaxf(r1[0], r1[1]));
            A[(size_t)b * APAD + c * 3721 + (15 * G + p) * 61 + pc] = fmaxf(v, 0.f);
        }
        if (G == 0)                                             // zero the K-pad tail
            for (int i2 = tid; i2 < 249; i2 += 256)
                A[(size_t)b * APAD + KFC + i2] = 0.f;
        __syncthreads();                                        // protect ex across reps
    }
}

// ============ fc1 split-K MFMA [r10-verbatim; measured r13: ~18.5 us] ============
// part[c][64 b][120 o]; grid (219,2); block 256 = 4 mtile waves; nth = N-half
__global__ __launch_bounds__(256) void fc1_s1(const float* __restrict__ A,
        const float* __restrict__ W, float* __restrict__ part) {
    const int cBlk = blockIdx.x;
    const int nth  = blockIdx.y;          // 0/1
    const int k0 = cBlk * CHUNK;
    const int tid = threadIdx.x;
    const int lane  = tid & 63;
    const int mtile = tid >> 6;           // 0..3
    const int ocol  = lane & 15;
    const int kq    = lane >> 4;          // 0..3 (k-quad within 32-wide MFMA K)
    const int arow  = mtile * 16 + ocol;

    const float* ab = A + (size_t)arow * APAD + k0 + kq * 8;
    const float* wb[4];
    #pragma unroll
    for (int ntl = 0; ntl < 4; ++ntl) {
        const int o = (nth * 4 + ntl) * 16 + ocol;
        wb[ntl] = W + (size_t)min(o, NFC1 - 1) * KFC + k0 + kq * 8;
    }

    f32x4 acc[4];
    #pragma unroll
    for (int n = 0; n < 4; ++n) acc[n] = (f32x4){0.f, 0.f, 0.f, 0.f};

    const bool full = (cBlk != NCHUNK - 1);
    #pragma unroll 2
    for (int ks = 0; ks < 8; ++ks) {
        float af[8];
        *(float4a*)&af[0] = *(const float4a*)(ab + ks * 32);
        *(float4a*)&af[4] = *(const float4a*)(ab + ks * 32 + 4);
        bfrag ah, al;
        #pragma unroll
        for (int e = 0; e < 8; ++e) {
            const unsigned u = __float_as_uint(af[e]);
            ah[e] = (short)(u >> 16);                            // hi = trunc-bf16
            const float rres = af[e] - __uint_as_float(u & 0xffff0000u);
            al[e] = (short)(__float_as_uint(rres) >> 16);        // lo = trunc-bf16(res)
        }
        #pragma unroll
        for (int ntl = 0; ntl < 4; ++ntl) {
            float wf[8];
            if (full) {
                *(float4a*)&wf[0] = *(const float4a*)(wb[ntl] + ks * 32);
                *(float4a*)&wf[4] = *(const float4a*)(wb[ntl] + ks * 32 + 4);
            } else {                                        // last chunk: guard OOB (W alloc end)
                const int kg = k0 + ks * 32 + kq * 8;
                #pragma unroll
                for (int e = 0; e < 8; ++e)
                    wf[e] = (kg + e < KFC) ? wb[ntl][ks * 32 + e] : 0.f;
            }
            bfrag wh, wl;
            #pragma unroll
            for (int e = 0; e < 8; ++e) {
                const unsigned u = __float_as_uint(wf[e]);
                wh[e] = (short)(u >> 16);
                const float rres = wf[e] - __uint_as_float(u & 0xffff0000u);
                wl[e] = (short)(__float_as_uint(rres) >> 16);
            }
            acc[ntl] = __builtin_amdgcn_mfma_f32_16x16x32_bf16(ah, wh, acc[ntl], 0, 0, 0);
            acc[ntl] = __builtin_amdgcn_mfma_f32_16x16x32_bf16(al, wh, acc[ntl], 0, 0, 0);
            acc[ntl] = __builtin_amdgcn_mfma_f32_16x16x32_bf16(ah, wl, acc[ntl], 0, 0, 0);
        }
    }
    #pragma unroll
    for (int ntl = 0; ntl < 4; ++ntl) {
        const int o = (nth * 4 + ntl) * 16 + ocol;
        if (o < NFC1) {
            #pragma unroll
            for (int rr = 0; rr < 4; ++rr) {
                const int brow = mtile * 16 + kq * 4 + rr;  // C/D: row=(l>>4)*4+reg, col=l&15
                part[((size_t)cBlk * 64 + brow) * NFC1 + o] = acc[ntl][rr];
            }
        }
    }
}

// ============ segment reduce: part2[8][7680] (219 = 3x28 + 5x27 chunks) ============
__global__ __launch_bounds__(256) void fc1_s2a(const float* __restrict__ part,
        float* __restrict__ part2) {
    const int idx = blockIdx.x * 256 + threadIdx.x;   // 61440
    const int seg = idx / 7680;
    const int r   = idx % 7680;
    const int c0 = seg * 27 + min(seg, 3);
    const int n  = 27 + (seg < 3 ? 1 : 0);
    float s = 0.f;
    for (int c = c0; c < c0 + n; ++c) s += part[(size_t)c * 7680 + r];
    part2[idx] = s;
}

// ============ tail: fc1 finish + fc2 rows 0..3 + fidelity + classifier + softmax ============
__global__ __launch_bounds__(64) void tail_k(const float* __restrict__ part2,
        const float* __restrict__ fc1b,
        const float* __restrict__ fc2w, const float* __restrict__ fc2b,
        const float* __restrict__ centers,
        const float* __restrict__ w1, const float* __restrict__ b1,
        const float* __restrict__ w2, const float* __restrict__ b2,
        const float* __restrict__ w3, const float* __restrict__ b3,
        float* __restrict__ out) {
    const int b = blockIdx.x;
    const int lane = threadIdx.x;
    __shared__ float h[120];
    __shared__ float feat[4];
    __shared__ float bufA[64];
    __shared__ float bufB[64];

    for (int o = lane; o < NFC1; o += 64) {
        float sv = fc1b[o];
        #pragma unroll
        for (int g = 0; g < 8; ++g) sv += part2[g * 7680 + b * NFC1 + o];
        h[o] = fmaxf(sv, 0.f);
    }
    __syncthreads();

    const int j = lane >> 4, p = lane & 15;
    float sv = 0.f;
    for (int o = p; o < NFC1; o += 16) sv = fmaf(fc2w[j * NFC1 + o], h[o], sv);
    #pragma unroll
    for (int off = 8; off; off >>= 1) sv += __shfl_xor(sv, off, 16);
    if (p == 0) feat[j] = fmaxf(sv + fc2b[j], 0.f);
    __syncthreads();

    float prod = 1.f;
    #pragma unroll
    for (int i = 0; i < 4; ++i) prod *= cosf(0.5f * (feat[i] - centers[lane * 84 + i]));
    bufA[lane] = fabsf(prod);
    __syncthreads();

    float s1 = b1[lane];
    for (int jj = 0; jj < 64; ++jj) s1 = fmaf(w1[lane * 64 + jj], bufA[jj], s1);
    bufB[lane] = fmaxf(s1, 0.f);
    __syncthreads();

    float s2 = b2[lane];
    for (int jj = 0; jj < 64; ++jj) s2 = fmaf(w2[lane * 64 + jj], bufB[jj], s2);
    bufA[lane] = fmaxf(s2, 0.f);
    __syncthreads();

    if (lane < 2) {
        float s3 = b3[lane];
        for (int jj = 0; jj < 64; ++jj) s3 = fmaf(w3[lane * 64 + jj], bufA[jj], s3);
        const float other = __shfl_xor(s3, 1, 2);
        const float m = fmaxf(s3, other);
        const float e = expf(s3 - m), eo = expf(other - m);
        out[b * 2 + lane] = e / (e + eo);
    }
}

// ---------------- launcher ----------------
extern "C" void kernel_launch(void* const* d_in, const int* in_sizes, int n_in,
                              void* d_out, int out_size, void* d_ws, size_t ws_size,
                              hipStream_t stream) {
    const float* x       = (const float*)d_in[0];
    const float* conv1_w = (const float*)d_in[1];
    const float* conv1_b = (const float*)d_in[2];
    const float* conv2_w = (const float*)d_in[3];
    const float* conv2_b = (const float*)d_in[4];
    const float* fc1_w   = (const float*)d_in[5];
    const float* fc1_b   = (const float*)d_in[6];
    const float* fc2_w   = (const float*)d_in[7];
    const float* fc2_b   = (const float*)d_in[8];
    const float* centers = (const float*)d_in[9];
    const float* cls_w1  = (const float*)d_in[10];
    const float* cls_b1  = (const float*)d_in[11];
    const float* cls_w2  = (const float*)d_in[12];
    const float* cls_b2  = (const float*)d_in[13];
    const float* cls_w3  = (const float*)d_in[14];
    const float* cls_b3  = (const float*)d_in[15];
    char* ws = (char*)d_ws;
    float* outp = (float*)d_out;

    float* p1    = (float*)(ws + oP1B);
    float* Abuf  = (float*)(ws + oAB);
    float* partb = (float*)(ws + oPARTB);
    float* part2 = (float*)(ws + oP2B);

    // DIAGNOSTIC: convs internally replicated x3 -> per-dispatch dur > fills -> counters visible.
    // conv2 = (dur - 86)/2 - 24.4
    hipLaunchKernelGGL(conv1_pool, dim3(18, 64), dim3(256), 0, stream, x, conv1_w, conv1_b, p1, 3);
    hipLaunchKernelGGL(conv2_pool, dim3(5, 64), dim3(256), 0, stream, p1, conv2_w, conv2_b, Abuf, 3);
    hipLaunchKernelGGL(fc1_s1, dim3(NCHUNK, 2), dim3(256), 0, stream, Abuf, fc1_w, partb);
    hipLaunchKernelGGL(fc1_s2a, dim3(240), dim3(256), 0, stream, partb, part2);
    hipLaunchKernelGGL(tail_k, dim3(64), dim3(64), 0, stream,
                       part2, fc1_b, fc2_w, fc2_b, centers,
                       cls_w1, cls_b1, cls_w2, cls_b2, cls_w3, cls_b3, outp);
}

// Round 16
// 96.005 us; speedup vs baseline: 1.9110x; 1.6700x over previous
//
#include <hip/hip_runtime.h>
#include <hip/hip_bf16.h>

typedef float float4a __attribute__((ext_vector_type(4), aligned(4)));
typedef float float2a __attribute__((ext_vector_type(2), aligned(4)));
typedef short bfrag   __attribute__((ext_vector_type(8)));   // 8 bf16 (MFMA A/B frag)
typedef float f32x4   __attribute__((ext_vector_type(4)));

// ---------------- dims ----------------
#define P1W_PAD 128            // p1 row stride (f32), cols 123..127 zero
#define APAD 56064             // A row stride (f32) = 219*256, elems 55815.. zero
#define KFC 55815
#define CHUNK 256
#define NCHUNK 219
#define NFC1 120

// ws byte offsets
#define oP1B   ((size_t)0)            // 24,182,784
#define oAB    ((size_t)24182784)     // 14,352,384
#define oPARTB ((size_t)38535168)     // 219*7680*4 = 6,727,680
#define oP2B   ((size_t)45262848)     // 8*7680*4   =   245,760

// ============ conv1 v2 (3->6,k5,s2,p1)+ReLU+pool2s1 -> p1 f32[64][6][123][128] ============
// block 128 = 8 conv rows (t) x 16 strips (s, 9 conv cols each); grid (18,64)
__global__ __launch_bounds__(128) void conv1_pool(const float* __restrict__ x,
        const float* __restrict__ w, const float* __restrict__ bias,
        float* __restrict__ p1) {
    __shared__ float ex[8 * 6 * 128];     // col-pooled values, 24.6 KB
    const int tid = threadIdx.x;
    const int G = blockIdx.x;             // 0..17
    const int b = blockIdx.y;
    const int t = tid >> 4;               // conv row slot 0..7
    const int s = tid & 15;               // strip: conv cols 8s..8s+8
    const int r = 7 * G + t;              // conv row

    if (r < 124) {
        float acc[6][9];
        #pragma unroll
        for (int c = 0; c < 6; ++c) {
            const float bz = bias[c];
            #pragma unroll
            for (int j = 0; j < 9; ++j) acc[c][j] = bz;
        }
        const int c0 = 16 * s;            // a[k] = input col c0-1+k
        for (int ic = 0; ic < 3; ++ic) {
            const float* xpl = x + (size_t)(b * 3 + ic) * 62500;
            #pragma unroll
            for (int ky = 0; ky < 5; ++ky) {
                const int iy = 2 * r - 1 + ky;
                if (iy < 0) continue;                       // top pad (bottom never hit)
                const float* rp = xpl + iy * 250 + c0;
                float a[21];
                a[0] = (s > 0) ? rp[-1] : 0.f;              // left pad
                if (s < 15) {                               // cols c0..c0+19 <= 243
                    *(float4a*)&a[1]  = *(const float4a*)rp;
                    *(float4a*)&a[5]  = *(const float4a*)(rp + 4);
                    *(float4a*)&a[9]  = *(const float4a*)(rp + 8);
                    *(float4a*)&a[13] = *(const float4a*)(rp + 12);
                    *(float4a*)&a[17] = *(const float4a*)(rp + 16);
                } else {                                    // s=15: cols 240..249 only
                    *(float4a*)&a[1]  = *(const float4a*)rp;        // 240..243
                    *(float4a*)&a[5]  = *(const float4a*)(rp + 4);  // 244..247
                    *(float2a*)&a[9]  = *(const float2a*)(rp + 8);  // 248,249
                    #pragma unroll
                    for (int k = 11; k < 21; ++k) a[k] = 0.f;       // cols >=250 (outputs masked)
                }
                const float* wb = w + ic * 25 + ky * 5;     // + c*75 + kx (uniform s_loads)
                #pragma unroll
                for (int c = 0; c < 6; ++c) {
                    #pragma unroll
                    for (int kx = 0; kx < 5; ++kx) {
                        const float wv = wb[c * 75 + kx];
                        #pragma unroll
                        for (int j = 0; j < 9; ++j)
                            acc[c][j] = fmaf(a[2 * j + kx], wv, acc[c][j]);
                    }
                }
            }
        }
        // in-register column pool -> ex[t][c][8s..8s+7]
        #pragma unroll
        for (int c = 0; c < 6; ++c) {
            float cm[8];
            #pragma unroll
            for (int pc = 0; pc < 8; ++pc)
                cm[pc] = fmaxf(acc[c][pc], acc[c][pc + 1]);
            *(float4*)&ex[(t * 6 + c) * 128 + 8 * s]     = *(float4*)&cm[0];
            *(float4*)&ex[(t * 6 + c) * 128 + 8 * s + 4] = *(float4*)&cm[4];
        }
    }
    __syncthreads();
    // row pool + relu + write (flat, conflict-free; pad cols 123..127 zeroed)
    for (int idx = tid; idx < 7 * 768; idx += 128) {        // 768 = 6*128
        const int p   = idx / 768;
        const int rem = idx - p * 768;                      // NOT & 767 (768 != 2^n)
        const int c   = rem >> 7;
        const int pc  = rem & 127;
        const int pr  = 7 * G + p;
        if (pr < 123) {
            float v = 0.f;
            if (pc < 123)
                v = fmaxf(fmaxf(ex[(p * 6 + c) * 128 + pc],
                                ex[((p + 1) * 6 + c) * 128 + pc]), 0.f);
            p1[((size_t)(b * 6 + c) * 123 + pr) * P1W_PAD + pc] = v;
        }
    }
}

// ============ conv2 v2 (6->15,k3,s2,p1)+ReLU+pool2s1 -> A f32[64][56064] ============
// grid (5, 64, 3): blockIdx.z = channel group of 5; block 256 = 16 rows x 16 strips
__global__ __launch_bounds__(256) void conv2_pool(const float* __restrict__ p1,
        const float* __restrict__ w, const float* __restrict__ bias,
        float* __restrict__ A) {
    __shared__ float ex[16 * 5 * 64];     // 20.5 KB
    const int tid = threadIdx.x;
    const int G = blockIdx.x;
    const int b = blockIdx.y;
    const int cb = blockIdx.z * 5;        // channel base
    const int t = tid >> 4;
    const int s = tid & 15;
    const int r = 15 * G + t;
    const bool act = (r < 62);

    if (act) {
        float acc[5][4];
        #pragma unroll
        for (int c = 0; c < 5; ++c) {
            const float bz = bias[cb + c];
            #pragma unroll
            for (int j = 0; j < 4; ++j) acc[c][j] = bz;
        }
        for (int ic = 0; ic < 6; ++ic) {
            const float* pl = p1 + (size_t)(b * 6 + ic) * 123 * P1W_PAD;
            #pragma unroll
            for (int ky = 0; ky < 3; ++ky) {
                const int iy = 2 * r - 1 + ky;
                if (iy < 0 || iy > 122) continue;
                const float* rp = pl + iy * P1W_PAD + 8 * s;
                float a[9];
                a[0] = (s > 0) ? rp[-1] : 0.f;              // left pad (cols>=123 are 0)
                *(float4a*)&a[1] = *(const float4a*)rp;
                *(float4a*)&a[5] = *(const float4a*)(rp + 4);
                const float* wb = w + ic * 9 + ky * 3;      // + (cb+c)*54 + kx (uniform)
                #pragma unroll
                for (int c = 0; c < 5; ++c) {
                    #pragma unroll
                    for (int kx = 0; kx < 3; ++kx) {
                        const float wv = wb[(cb + c) * 54 + kx];
                        #pragma unroll
                        for (int j = 0; j < 4; ++j)
                            acc[c][j] = fmaf(a[2 * j + kx], wv, acc[c][j]);
                    }
                }
            }
        }
        #pragma unroll
        for (int c = 0; c < 5; ++c)
            *(float4*)&ex[(t * 5 + c) * 64 + 4 * s] = *(float4*)&acc[c][0];
    }
    __syncthreads();
    const int np = min(15, 61 - 15 * G);
    for (int idx = tid; idx < np * 305; idx += 256) {       // 305 = 5*61 (true modulo)
        const int p   = idx / 305;
        const int rem = idx % 305;
        const int c   = rem / 61;
        const int pc  = rem % 61;
        const float* r0 = &ex[((p    ) * 5 + c) * 64 + pc];
        const float* r1 = &ex[((p + 1) * 5 + c) * 64 + pc];
        const float v = fmaxf(fmaxf(r0[0], r0[1]), fmaxf(r1[0], r1[1]));
        A[(size_t)b * APAD + (cb + c) * 3721 + (15 * G + p) * 61 + pc] = fmaxf(v, 0.f);
    }
    if (G == 0 && cb == 0)                                  // zero the K-pad tail (once)
        for (int i2 = tid; i2 < 249; i2 += 256)
            A[(size_t)b * APAD + KFC + i2] = 0.f;
}

// ============ fc1 split-K MFMA [r10-verbatim; measured r13: ~18.5 us] ============
// part[c][64 b][120 o]; grid (219,2); block 256 = 4 mtile waves; nth = N-half
__global__ __launch_bounds__(256) void fc1_s1(const float* __restrict__ A,
        const float* __restrict__ W, float* __restrict__ part) {
    const int cBlk = blockIdx.x;
    const int nth  = blockIdx.y;          // 0/1
    const int k0 = cBlk * CHUNK;
    const int tid = threadIdx.x;
    const int lane  = tid & 63;
    const int mtile = tid >> 6;           // 0..3
    const int ocol  = lane & 15;
    const int kq    = lane >> 4;          // 0..3 (k-quad within 32-wide MFMA K)
    const int arow  = mtile * 16 + ocol;

    const float* ab = A + (size_t)arow * APAD + k0 + kq * 8;
    const float* wb[4];
    #pragma unroll
    for (int ntl = 0; ntl < 4; ++ntl) {
        const int o = (nth * 4 + ntl) * 16 + ocol;
        wb[ntl] = W + (size_t)min(o, NFC1 - 1) * KFC + k0 + kq * 8;
    }

    f32x4 acc[4];
    #pragma unroll
    for (int n = 0; n < 4; ++n) acc[n] = (f32x4){0.f, 0.f, 0.f, 0.f};

    const bool full = (cBlk != NCHUNK - 1);
    #pragma unroll 2
    for (int ks = 0; ks < 8; ++ks) {
        float af[8];
        *(float4a*)&af[0] = *(const float4a*)(ab + ks * 32);
        *(float4a*)&af[4] = *(const float4a*)(ab + ks * 32 + 4);
        bfrag ah, al;
        #pragma unroll
        for (int e = 0; e < 8; ++e) {
            const unsigned u = __float_as_uint(af[e]);
            ah[e] = (short)(u >> 16);                            // hi = trunc-bf16
            const float rres = af[e] - __uint_as_float(u & 0xffff0000u);
            al[e] = (short)(__float_as_uint(rres) >> 16);        // lo = trunc-bf16(res)
        }
        #pragma unroll
        for (int ntl = 0; ntl < 4; ++ntl) {
            float wf[8];
            if (full) {
                *(float4a*)&wf[0] = *(const float4a*)(wb[ntl] + ks * 32);
                *(float4a*)&wf[4] = *(const float4a*)(wb[ntl] + ks * 32 + 4);
            } else {                                        // last chunk: guard OOB (W alloc end)
                const int kg = k0 + ks * 32 + kq * 8;
                #pragma unroll
                for (int e = 0; e < 8; ++e)
                    wf[e] = (kg + e < KFC) ? wb[ntl][ks * 32 + e] : 0.f;
            }
            bfrag wh, wl;
            #pragma unroll
            for (int e = 0; e < 8; ++e) {
                const unsigned u = __float_as_uint(wf[e]);
                wh[e] = (short)(u >> 16);
                const float rres = wf[e] - __uint_as_float(u & 0xffff0000u);
                wl[e] = (short)(__float_as_uint(rres) >> 16);
            }
            acc[ntl] = __builtin_amdgcn_mfma_f32_16x16x32_bf16(ah, wh, acc[ntl], 0, 0, 0);
            acc[ntl] = __builtin_amdgcn_mfma_f32_16x16x32_bf16(al, wh, acc[ntl], 0, 0, 0);
            acc[ntl] = __builtin_amdgcn_mfma_f32_16x16x32_bf16(ah, wl, acc[ntl], 0, 0, 0);
        }
    }
    #pragma unroll
    for (int ntl = 0; ntl < 4; ++ntl) {
        const int o = (nth * 4 + ntl) * 16 + ocol;
        if (o < NFC1) {
            #pragma unroll
            for (int rr = 0; rr < 4; ++rr) {
                const int brow = mtile * 16 + kq * 4 + rr;  // C/D: row=(l>>4)*4+reg, col=l&15
                part[((size_t)cBlk * 64 + brow) * NFC1 + o] = acc[ntl][rr];
            }
        }
    }
}

// ============ segment reduce: part2[8][7680] (219 = 3x28 + 5x27 chunks) ============
__global__ __launch_bounds__(256) void fc1_s2a(const float* __restrict__ part,
        float* __restrict__ part2) {
    const int idx = blockIdx.x * 256 + threadIdx.x;   // 61440
    const int seg = idx / 7680;
    const int r   = idx % 7680;
    const int c0 = seg * 27 + min(seg, 3);
    const int n  = 27 + (seg < 3 ? 1 : 0);
    float s = 0.f;
    for (int c = c0; c < c0 + n; ++c) s += part[(size_t)c * 7680 + r];
    part2[idx] = s;
}

// ============ tail: fc1 finish + fc2 rows 0..3 + fidelity + classifier + softmax ============
__global__ __launch_bounds__(64) void tail_k(const float* __restrict__ part2,
        const float* __restrict__ fc1b,
        const float* __restrict__ fc2w, const float* __restrict__ fc2b,
        const float* __restrict__ centers,
        const float* __restrict__ w1, const float* __restrict__ b1,
        const float* __restrict__ w2, const float* __restrict__ b2,
        const float* __restrict__ w3, const float* __restrict__ b3,
        float* __restrict__ out) {
    const int b = blockIdx.x;
    const int lane = threadIdx.x;
    __shared__ float h[120];
    __shared__ float feat[4];
    __shared__ float bufA[64];
    __shared__ float bufB[64];

    for (int o = lane; o < NFC1; o += 64) {
        float sv = fc1b[o];
        #pragma unroll
        for (int g = 0; g < 8; ++g) sv += part2[g * 7680 + b * NFC1 + o];
        h[o] = fmaxf(sv, 0.f);
    }
    __syncthreads();

    const int j = lane >> 4, p = lane & 15;
    float sv = 0.f;
    for (int o = p; o < NFC1; o += 16) sv = fmaf(fc2w[j * NFC1 + o], h[o], sv);
    #pragma unroll
    for (int off = 8; off; off >>= 1) sv += __shfl_xor(sv, off, 16);
    if (p == 0) feat[j] = fmaxf(sv + fc2b[j], 0.f);
    __syncthreads();

    float prod = 1.f;
    #pragma unroll
    for (int i = 0; i < 4; ++i) prod *= cosf(0.5f * (feat[i] - centers[lane * 84 + i]));
    bufA[lane] = fabsf(prod);
    __syncthreads();

    float s1 = b1[lane];
    for (int jj = 0; jj < 64; ++jj) s1 = fmaf(w1[lane * 64 + jj], bufA[jj], s1);
    bufB[lane] = fmaxf(s1, 0.f);
    __syncthreads();

    float s2 = b2[lane];
    for (int jj = 0; jj < 64; ++jj) s2 = fmaf(w2[lane * 64 + jj], bufB[jj], s2);
    bufA[lane] = fmaxf(s2, 0.f);
    __syncthreads();

    if (lane < 2) {
        float s3 = b3[lane];
        for (int jj = 0; jj < 64; ++jj) s3 = fmaf(w3[lane * 64 + jj], bufA[jj], s3);
        const float other = __shfl_xor(s3, 1, 2);
        const float m = fmaxf(s3, other);
        const float e = expf(s3 - m), eo = expf(other - m);
        out[b * 2 + lane] = e / (e + eo);
    }
}

// ---------------- launcher ----------------
extern "C" void kernel_launch(void* const* d_in, const int* in_sizes, int n_in,
                              void* d_out, int out_size, void* d_ws, size_t ws_size,
                              hipStream_t stream) {
    const float* x       = (const float*)d_in[0];
    const float* conv1_w = (const float*)d_in[1];
    const float* conv1_b = (const float*)d_in[2];
    const float* conv2_w = (const float*)d_in[3];
    const float* conv2_b = (const float*)d_in[4];
    const float* fc1_w   = (const float*)d_in[5];
    const float* fc1_b   = (const float*)d_in[6];
    const float* fc2_w   = (const float*)d_in[7];
    const float* fc2_b   = (const float*)d_in[8];
    const float* centers = (const float*)d_in[9];
    const float* cls_w1  = (const float*)d_in[10];
    const float* cls_b1  = (const float*)d_in[11];
    const float* cls_w2  = (const float*)d_in[12];
    const float* cls_b2  = (const float*)d_in[13];
    const float* cls_w3  = (const float*)d_in[14];
    const float* cls_b3  = (const float*)d_in[15];
    char* ws = (char*)d_ws;
    float* outp = (float*)d_out;

    float* p1    = (float*)(ws + oP1B);
    float* Abuf  = (float*)(ws + oAB);
    float* partb = (float*)(ws + oPARTB);
    float* part2 = (float*)(ws + oP2B);

    hipLaunchKernelGGL(conv1_pool, dim3(18, 64), dim3(128), 0, stream, x, conv1_w, conv1_b, p1);
    hipLaunchKernelGGL(conv2_pool, dim3(5, 64, 3), dim3(256), 0, stream, p1, conv2_w, conv2_b, Abuf);
    hipLaunchKernelGGL(fc1_s1, dim3(NCHUNK, 2), dim3(256), 0, stream, Abuf, fc1_w, partb);
    hipLaunchKernelGGL(fc1_s2a, dim3(240), dim3(256), 0, stream, partb, part2);
    hipLaunchKernelGGL(tail_k, dim3(64), dim3(64), 0, stream,
                       part2, fc1_b, fc2_w, fc2_b, centers,
                       cls_w1, cls_b1, cls_w2, cls_b2, cls_w3, cls_b3, outp);
}

// Round 17
// 83.247 us; speedup vs baseline: 2.2038x; 1.1533x over previous
//
#include <hip/hip_runtime.h>
#include <hip/hip_bf16.h>

typedef float float4a __attribute__((ext_vector_type(4), aligned(4)));
typedef float float2a __attribute__((ext_vector_type(2), aligned(4)));
typedef short bfrag   __attribute__((ext_vector_type(8)));   // 8 bf16 (MFMA A/B frag)
typedef float f32x4   __attribute__((ext_vector_type(4)));

// ---------------- dims ----------------
#define P1W_PAD 128            // p1 row stride (f32), cols 123..127 zero
#define APAD 56064             // A row stride (f32) = 219*256, elems 55815.. zero
#define KFC 55815
#define CHUNK 256
#define NCHUNK 219
#define NFC1 120

// ws byte offsets
#define oP1B   ((size_t)0)            // 24,182,784
#define oAB    ((size_t)24182784)     // 14,352,384
#define oPARTB ((size_t)38535168)     // 219*7680*4 = 6,727,680
#define oP2B   ((size_t)45262848)     // 8*7680*4   =   245,760

// ============ conv1 v3 (3->6,k5,s2,p1)+ReLU+pool2s1 -> p1 f32[64][6][123][128] ============
// block 256 = 4 conv rows (t) x 64 strips (s, 2 conv cols); grid (41,64) -> 10496 waves (occ cap)
__global__ __launch_bounds__(256) void conv1_pool(const float* __restrict__ x,
        const float* __restrict__ w, const float* __restrict__ bias,
        float* __restrict__ p1) {
    __shared__ float ex[4 * 6 * 128];     // 12.3 KB
    const int tid = threadIdx.x;
    const int G = blockIdx.x;             // 0..40 (3 pool rows each; 41*3 = 123)
    const int b = blockIdx.y;
    const int t = tid >> 6;               // conv row slot 0..3
    const int s = tid & 63;               // strip: conv cols 2s, 2s+1
    const int r = 3 * G + t;              // conv row, max 123 (<124)
    const bool act = (s < 62);            // conv cols <= 123

    if (act) {
        float acc[6][2];
        #pragma unroll
        for (int c = 0; c < 6; ++c) {
            const float bz = bias[c];
            acc[c][0] = bz; acc[c][1] = bz;
        }
        for (int ic = 0; ic < 3; ++ic) {
            const float* xpl = x + (size_t)(b * 3 + ic) * 62500;
            #pragma unroll
            for (int ky = 0; ky < 5; ++ky) {
                const int iy = 2 * r - 1 + ky;
                if (iy < 0) continue;                       // top pad (bottom never hit: iy<=249)
                const float* rp = xpl + iy * 250 + 4 * s;
                float a[7];                                 // input cols 4s-1 .. 4s+5
                a[0] = (s > 0) ? rp[-1] : 0.f;              // left pad
                *(float4a*)&a[1] = *(const float4a*)rp;     // 4s..4s+3 (s=61 -> 244..247 ok)
                *(float2a*)&a[5] = *(const float2a*)(rp + 4); // 4s+4,4s+5 (s=61 -> 248,249 ok)
                const float* wb = w + ic * 25 + ky * 5;     // + c*75 + kx (uniform s_loads)
                #pragma unroll
                for (int c = 0; c < 6; ++c) {
                    #pragma unroll
                    for (int kx = 0; kx < 5; ++kx) {
                        const float wv = wb[c * 75 + kx];
                        acc[c][0] = fmaf(a[kx],     wv, acc[c][0]);   // conv col 2s
                        acc[c][1] = fmaf(a[kx + 2], wv, acc[c][1]);   // conv col 2s+1
                    }
                }
            }
        }
        #pragma unroll
        for (int c = 0; c < 6; ++c)
            *(float2*)&ex[(t * 6 + c) * 128 + 2 * s] = make_float2(acc[c][0], acc[c][1]);
    }
    __syncthreads();
    // pool 3 rows (conv rows t..t+1) + relu + padded write
    for (int idx = tid; idx < 3 * 768; idx += 256) {        // 768 = 6*128
        const int p   = idx / 768;
        const int rem = idx - p * 768;                      // NOT & 767 (768 != 2^n)
        const int c   = rem >> 7;
        const int pc  = rem & 127;
        const int pr  = 3 * G + p;                          // <= 122 always
        float v = 0.f;
        if (pc < 123) {
            const float* r0 = &ex[((p    ) * 6 + c) * 128 + pc];
            const float* r1 = &ex[((p + 1) * 6 + c) * 128 + pc];
            v = fmaxf(fmaxf(fmaxf(r0[0], r0[1]), fmaxf(r1[0], r1[1])), 0.f);
        }
        p1[((size_t)(b * 6 + c) * 123 + pr) * P1W_PAD + pc] = v;
    }
}

// ============ conv2 v2 (6->15,k3,s2,p1)+ReLU+pool2s1 -> A f32[64][56064] [r16-proven] ============
// grid (5, 64, 3): blockIdx.z = channel group of 5; block 256 = 16 rows x 16 strips
__global__ __launch_bounds__(256) void conv2_pool(const float* __restrict__ p1,
        const float* __restrict__ w, const float* __restrict__ bias,
        float* __restrict__ A) {
    __shared__ float ex[16 * 5 * 64];     // 20.5 KB
    const int tid = threadIdx.x;
    const int G = blockIdx.x;
    const int b = blockIdx.y;
    const int cb = blockIdx.z * 5;        // channel base
    const int t = tid >> 4;
    const int s = tid & 15;
    const int r = 15 * G + t;
    const bool act = (r < 62);

    if (act) {
        float acc[5][4];
        #pragma unroll
        for (int c = 0; c < 5; ++c) {
            const float bz = bias[cb + c];
            #pragma unroll
            for (int j = 0; j < 4; ++j) acc[c][j] = bz;
        }
        for (int ic = 0; ic < 6; ++ic) {
            const float* pl = p1 + (size_t)(b * 6 + ic) * 123 * P1W_PAD;
            #pragma unroll
            for (int ky = 0; ky < 3; ++ky) {
                const int iy = 2 * r - 1 + ky;
                if (iy < 0 || iy > 122) continue;
                const float* rp = pl + iy * P1W_PAD + 8 * s;
                float a[9];
                a[0] = (s > 0) ? rp[-1] : 0.f;              // left pad (cols>=123 are 0)
                *(float4a*)&a[1] = *(const float4a*)rp;
                *(float4a*)&a[5] = *(const float4a*)(rp + 4);
                const float* wb = w + ic * 9 + ky * 3;      // + (cb+c)*54 + kx (uniform)
                #pragma unroll
                for (int c = 0; c < 5; ++c) {
                    #pragma unroll
                    for (int kx = 0; kx < 3; ++kx) {
                        const float wv = wb[(cb + c) * 54 + kx];
                        #pragma unroll
                        for (int j = 0; j < 4; ++j)
                            acc[c][j] = fmaf(a[2 * j + kx], wv, acc[c][j]);
                    }
                }
            }
        }
        #pragma unroll
        for (int c = 0; c < 5; ++c)
            *(float4*)&ex[(t * 5 + c) * 64 + 4 * s] = *(float4*)&acc[c][0];
    }
    __syncthreads();
    const int np = min(15, 61 - 15 * G);
    for (int idx = tid; idx < np * 305; idx += 256) {       // 305 = 5*61 (true modulo)
        const int p   = idx / 305;
        const int rem = idx % 305;
        const int c   = rem / 61;
        const int pc  = rem % 61;
        const float* r0 = &ex[((p    ) * 5 + c) * 64 + pc];
        const float* r1 = &ex[((p + 1) * 5 + c) * 64 + pc];
        const float v = fmaxf(fmaxf(r0[0], r0[1]), fmaxf(r1[0], r1[1]));
        A[(size_t)b * APAD + (cb + c) * 3721 + (15 * G + p) * 61 + pc] = fmaxf(v, 0.f);
    }
    if (G == 0 && cb == 0)                                  // zero the K-pad tail (once)
        for (int i2 = tid; i2 < 249; i2 += 256)
            A[(size_t)b * APAD + KFC + i2] = 0.f;
}

// ============ fc1 split-K MFMA [r10-verbatim; measured r13: ~18.5 us] ============
// part[c][64 b][120 o]; grid (219,2); block 256 = 4 mtile waves; nth = N-half
__global__ __launch_bounds__(256) void fc1_s1(const float* __restrict__ A,
        const float* __restrict__ W, float* __restrict__ part) {
    const int cBlk = blockIdx.x;
    const int nth  = blockIdx.y;          // 0/1
    const int k0 = cBlk * CHUNK;
    const int tid = threadIdx.x;
    const int lane  = tid & 63;
    const int mtile = tid >> 6;           // 0..3
    const int ocol  = lane & 15;
    const int kq    = lane >> 4;          // 0..3 (k-quad within 32-wide MFMA K)
    const int arow  = mtile * 16 + ocol;

    const float* ab = A + (size_t)arow * APAD + k0 + kq * 8;
    const float* wb[4];
    #pragma unroll
    for (int ntl = 0; ntl < 4; ++ntl) {
        const int o = (nth * 4 + ntl) * 16 + ocol;
        wb[ntl] = W + (size_t)min(o, NFC1 - 1) * KFC + k0 + kq * 8;
    }

    f32x4 acc[4];
    #pragma unroll
    for (int n = 0; n < 4; ++n) acc[n] = (f32x4){0.f, 0.f, 0.f, 0.f};

    const bool full = (cBlk != NCHUNK - 1);
    #pragma unroll 2
    for (int ks = 0; ks < 8; ++ks) {
        float af[8];
        *(float4a*)&af[0] = *(const float4a*)(ab + ks * 32);
        *(float4a*)&af[4] = *(const float4a*)(ab + ks * 32 + 4);
        bfrag ah, al;
        #pragma unroll
        for (int e = 0; e < 8; ++e) {
            const unsigned u = __float_as_uint(af[e]);
            ah[e] = (short)(u >> 16);                            // hi = trunc-bf16
            const float rres = af[e] - __uint_as_float(u & 0xffff0000u);
            al[e] = (short)(__float_as_uint(rres) >> 16);        // lo = trunc-bf16(res)
        }
        #pragma unroll
        for (int ntl = 0; ntl < 4; ++ntl) {
            float wf[8];
            if (full) {
                *(float4a*)&wf[0] = *(const float4a*)(wb[ntl] + ks * 32);
                *(float4a*)&wf[4] = *(const float4a*)(wb[ntl] + ks * 32 + 4);
            } else {                                        // last chunk: guard OOB (W alloc end)
                const int kg = k0 + ks * 32 + kq * 8;
                #pragma unroll
                for (int e = 0; e < 8; ++e)
                    wf[e] = (kg + e < KFC) ? wb[ntl][ks * 32 + e] : 0.f;
            }
            bfrag wh, wl;
            #pragma unroll
            for (int e = 0; e < 8; ++e) {
                const unsigned u = __float_as_uint(wf[e]);
                wh[e] = (short)(u >> 16);
                const float rres = wf[e] - __uint_as_float(u & 0xffff0000u);
                wl[e] = (short)(__float_as_uint(rres) >> 16);
            }
            acc[ntl] = __builtin_amdgcn_mfma_f32_16x16x32_bf16(ah, wh, acc[ntl], 0, 0, 0);
            acc[ntl] = __builtin_amdgcn_mfma_f32_16x16x32_bf16(al, wh, acc[ntl], 0, 0, 0);
            acc[ntl] = __builtin_amdgcn_mfma_f32_16x16x32_bf16(ah, wl, acc[ntl], 0, 0, 0);
        }
    }
    #pragma unroll
    for (int ntl = 0; ntl < 4; ++ntl) {
        const int o = (nth * 4 + ntl) * 16 + ocol;
        if (o < NFC1) {
            #pragma unroll
            for (int rr = 0; rr < 4; ++rr) {
                const int brow = mtile * 16 + kq * 4 + rr;  // C/D: row=(l>>4)*4+reg, col=l&15
                part[((size_t)cBlk * 64 + brow) * NFC1 + o] = acc[ntl][rr];
            }
        }
    }
}

// ============ segment reduce: part2[8][7680] (219 = 3x28 + 5x27 chunks) ============
__global__ __launch_bounds__(256) void fc1_s2a(const float* __restrict__ part,
        float* __restrict__ part2) {
    const int idx = blockIdx.x * 256 + threadIdx.x;   // 61440
    const int seg = idx / 7680;
    const int r   = idx % 7680;
    const int c0 = seg * 27 + min(seg, 3);
    const int n  = 27 + (seg < 3 ? 1 : 0);
    float s = 0.f;
    for (int c = c0; c < c0 + n; ++c) s += part[(size_t)c * 7680 + r];
    part2[idx] = s;
}

// ============ tail: fc1 finish + fc2 rows 0..3 + fidelity + classifier + softmax ============
__global__ __launch_bounds__(64) void tail_k(const float* __restrict__ part2,
        const float* __restrict__ fc1b,
        const float* __restrict__ fc2w, const float* __restrict__ fc2b,
        const float* __restrict__ centers,
        const float* __restrict__ w1, const float* __restrict__ b1,
        const float* __restrict__ w2, const float* __restrict__ b2,
        const float* __restrict__ w3, const float* __restrict__ b3,
        float* __restrict__ out) {
    const int b = blockIdx.x;
    const int lane = threadIdx.x;
    __shared__ float h[120];
    __shared__ float feat[4];
    __shared__ float bufA[64];
    __shared__ float bufB[64];

    for (int o = lane; o < NFC1; o += 64) {
        float sv = fc1b[o];
        #pragma unroll
        for (int g = 0; g < 8; ++g) sv += part2[g * 7680 + b * NFC1 + o];
        h[o] = fmaxf(sv, 0.f);
    }
    __syncthreads();

    const int j = lane >> 4, p = lane & 15;
    float sv = 0.f;
    for (int o = p; o < NFC1; o += 16) sv = fmaf(fc2w[j * NFC1 + o], h[o], sv);
    #pragma unroll
    for (int off = 8; off; off >>= 1) sv += __shfl_xor(sv, off, 16);
    if (p == 0) feat[j] = fmaxf(sv + fc2b[j], 0.f);
    __syncthreads();

    float prod = 1.f;
    #pragma unroll
    for (int i = 0; i < 4; ++i) prod *= cosf(0.5f * (feat[i] - centers[lane * 84 + i]));
    bufA[lane] = fabsf(prod);
    __syncthreads();

    float s1 = b1[lane];
    for (int jj = 0; jj < 64; ++jj) s1 = fmaf(w1[lane * 64 + jj], bufA[jj], s1);
    bufB[lane] = fmaxf(s1, 0.f);
    __syncthreads();

    float s2 = b2[lane];
    for (int jj = 0; jj < 64; ++jj) s2 = fmaf(w2[lane * 64 + jj], bufB[jj], s2);
    bufA[lane] = fmaxf(s2, 0.f);
    __syncthreads();

    if (lane < 2) {
        float s3 = b3[lane];
        for (int jj = 0; jj < 64; ++jj) s3 = fmaf(w3[lane * 64 + jj], bufA[jj], s3);
        const float other = __shfl_xor(s3, 1, 2);
        const float m = fmaxf(s3, other);
        const float e = expf(s3 - m), eo = expf(other - m);
        out[b * 2 + lane] = e / (e + eo);
    }
}

// ---------------- launcher ----------------
extern "C" void kernel_launch(void* const* d_in, const int* in_sizes, int n_in,
                              void* d_out, int out_size, void* d_ws, size_t ws_size,
                              hipStream_t stream) {
    const float* x       = (const float*)d_in[0];
    const float* conv1_w = (const float*)d_in[1];
    const float* conv1_b = (const float*)d_in[2];
    const float* conv2_w = (const float*)d_in[3];
    const float* conv2_b = (const float*)d_in[4];
    const float* fc1_w   = (const float*)d_in[5];
    const float* fc1_b   = (const float*)d_in[6];
    const float* fc2_w   = (const float*)d_in[7];
    const float* fc2_b   = (const float*)d_in[8];
    const float* centers = (const float*)d_in[9];
    const float* cls_w1  = (const float*)d_in[10];
    const float* cls_b1  = (const float*)d_in[11];
    const float* cls_w2  = (const float*)d_in[12];
    const float* cls_b2  = (const float*)d_in[13];
    const float* cls_w3  = (const float*)d_in[14];
    const float* cls_b3  = (const float*)d_in[15];
    char* ws = (char*)d_ws;
    float* outp = (float*)d_out;

    float* p1    = (float*)(ws + oP1B);
    float* Abuf  = (float*)(ws + oAB);
    float* partb = (float*)(ws + oPARTB);
    float* part2 = (float*)(ws + oP2B);

    hipLaunchKernelGGL(conv1_pool, dim3(41, 64), dim3(256), 0, stream, x, conv1_w, conv1_b, p1);
    hipLaunchKernelGGL(conv2_pool, dim3(5, 64, 3), dim3(256), 0, stream, p1, conv2_w, conv2_b, Abuf);
    hipLaunchKernelGGL(fc1_s1, dim3(NCHUNK, 2), dim3(256), 0, stream, Abuf, fc1_w, partb);
    hipLaunchKernelGGL(fc1_s2a, dim3(240), dim3(256), 0, stream, partb, part2);
    hipLaunchKernelGGL(tail_k, dim3(64), dim3(64), 0, stream,
                       part2, fc1_b, fc2_w, fc2_b, centers,
                       cls_w1, cls_b1, cls_w2, cls_b2, cls_w3, cls_b3, outp);
}